// Round 1
// baseline (296.330 us; speedup 1.0000x reference)
//
#include <hip/hip_runtime.h>
#include <hip/hip_bf16.h>

// Shapes (fixed by setup_inputs):
// out_temporal: (16,24,128,32,32) f32  -> 50331648 elems
// gt:           (16,24,128,128)   int  -> 6291456 elems
// positions:    (16,24)           int  -> 384
// sits_id:      (16,)             int  -> 16
//
// Outputs (flat f32 in d_out, return order):
//   emb    (16,24,1,128) = 49152 @ 0
//   labels (16,24,1)     = 384   @ 49152
//   sits_id (16,)        = 16    @ 49536
//   positions (16,24)    = 384   @ 49552

#define NCHAN     49152      // B*T*C
#define SPATIAL   1024       // 32*32
#define NBT       384        // B*T
#define PIX_PER_BT 16384     // 128*128
#define NUM_CLASSES 6

#define OFF_EMB   0
#define OFF_LAB   49152
#define OFF_SITS  49536
#define OFF_POS   49552

// One wave (64 lanes) reduces one channel of 1024 contiguous floats.
__global__ void mean_pool_kernel(const float* __restrict__ in,
                                 float* __restrict__ out) {
    const int lane  = threadIdx.x & 63;
    const int wave  = (blockIdx.x * blockDim.x + threadIdx.x) >> 6;
    const int nwave = (gridDim.x * blockDim.x) >> 6;
    for (int c = wave; c < NCHAN; c += nwave) {
        const float4* p = (const float4*)(in + (size_t)c * SPATIAL);
        float s = 0.0f;
#pragma unroll
        for (int i = 0; i < 4; ++i) {
            float4 v = p[lane + 64 * i];   // coalesced 16B/lane
            s += (v.x + v.y) + (v.z + v.w);
        }
#pragma unroll
        for (int off = 32; off > 0; off >>= 1)
            s += __shfl_down(s, off, 64);
        if (lane == 0)
            out[OFF_EMB + c] = s * (1.0f / (float)SPATIAL);
    }
}

// One 256-thread block per (b,t): majority over 16384 pixels, 6 classes.
// Compile-time-indexed register counters (runtime-indexed arrays spill).
__global__ void majority_kernel(const int* __restrict__ gt,
                                const int* __restrict__ positions,
                                const int* __restrict__ sits_id,
                                float* __restrict__ out) {
    const int bt = blockIdx.x;          // 0..383
    const int4* p4 = (const int4*)(gt + (size_t)bt * PIX_PER_BT);

    int cnt[NUM_CLASSES] = {0, 0, 0, 0, 0, 0};
    // 16384 pixels / 4 per int4 = 4096 int4; 256 threads -> 16 int4/thread
    for (int i = threadIdx.x; i < PIX_PER_BT / 4; i += 256) {
        int4 v = p4[i];
#pragma unroll
        for (int c = 0; c < NUM_CLASSES; ++c) {
            cnt[c] += (v.x == c) + (v.y == c) + (v.z == c) + (v.w == c);
        }
    }

    __shared__ int scnt[NUM_CLASSES];
    if (threadIdx.x < NUM_CLASSES) scnt[threadIdx.x] = 0;
    __syncthreads();

#pragma unroll
    for (int c = 0; c < NUM_CLASSES; ++c) {
        int s = cnt[c];
#pragma unroll
        for (int off = 32; off > 0; off >>= 1)
            s += __shfl_down(s, off, 64);
        if ((threadIdx.x & 63) == 0) atomicAdd(&scnt[c], s);
    }
    __syncthreads();

    if (threadIdx.x == 0) {
        int best = 0, bc = scnt[0];
#pragma unroll
        for (int c = 1; c < NUM_CLASSES; ++c) {
            if (scnt[c] > bc) { bc = scnt[c]; best = c; }  // strict > keeps first-max (argmax semantics)
        }
        out[OFF_LAB + bt] = (float)best;
        out[OFF_POS + bt] = (float)positions[bt];
        if (bt < 16) out[OFF_SITS + bt] = (float)sits_id[bt];
    }
}

extern "C" void kernel_launch(void* const* d_in, const int* in_sizes, int n_in,
                              void* d_out, int out_size, void* d_ws, size_t ws_size,
                              hipStream_t stream) {
    const float* out_temporal = (const float*)d_in[0];
    const int*   gt           = (const int*)d_in[1];
    const int*   positions    = (const int*)d_in[2];
    const int*   sits_id      = (const int*)d_in[3];
    float*       out          = (float*)d_out;

    // Kernel 1: 2048 blocks x 256 thr = 8192 waves; 49152 channels -> 6/wave.
    mean_pool_kernel<<<2048, 256, 0, stream>>>(out_temporal, out);

    // Kernel 2: one block per (b,t); also writes pass-through outputs.
    majority_kernel<<<NBT, 256, 0, stream>>>(gt, positions, sits_id, out);
}

// Round 2
// 292.094 us; speedup vs baseline: 1.0145x; 1.0145x over previous
//
#include <hip/hip_runtime.h>
#include <hip/hip_bf16.h>

// Shapes (fixed by setup_inputs):
// out_temporal: (16,24,128,32,32) f32  -> 50331648 elems
// gt:           (16,24,128,128)   int  -> 6291456 elems
// positions:    (16,24)           int  -> 384
// sits_id:      (16,)             int  -> 16
//
// Outputs (flat f32 in d_out, return order):
//   emb    (16,24,1,128) = 49152 @ 0
//   labels (16,24,1)     = 384   @ 49152
//   sits_id (16,)        = 16    @ 49536
//   positions (16,24)    = 384   @ 49552

#define NCHAN       49152      // B*T*C
#define SPATIAL     1024       // 32*32
#define NBT         384        // B*T
#define PIX_PER_BT  16384      // 128*128
#define NUM_CLASSES 6

#define OFF_EMB   0
#define OFF_LAB   49152
#define OFF_SITS  49536
#define OFF_POS   49552

#define MEAN_BLOCKS 768        // 768 blocks * 16 waves * 4 ch = 49152 channels
#define TOTAL_BLOCKS (MEAN_BLOCKS + NBT)

// Fused kernel: blocks [0,768) = mean pool, blocks [768,1152) = majority+passthrough.
// 1024 threads/block. Single launch so both memory streams overlap.
__global__ __launch_bounds__(1024) void fused_kernel(
        const float* __restrict__ in,
        const int*  __restrict__ gt,
        const int*  __restrict__ positions,
        const int*  __restrict__ sits_id,
        float* __restrict__ out) {
    const int tid  = threadIdx.x;
    const int lane = tid & 63;
    const int wave = tid >> 6;          // 0..15

    if (blockIdx.x < MEAN_BLOCKS) {
        // ---- mean pooling: each wave reduces 4 channels (16 KB) ----
        const int c0 = blockIdx.x * 64 + wave * 4;
        const float4* p0 = (const float4*)(in + (size_t)(c0 + 0) * SPATIAL);
        const float4* p1 = (const float4*)(in + (size_t)(c0 + 1) * SPATIAL);
        const float4* p2 = (const float4*)(in + (size_t)(c0 + 2) * SPATIAL);
        const float4* p3 = (const float4*)(in + (size_t)(c0 + 3) * SPATIAL);

        // 16 independent float4 loads issued back-to-back (MLP).
        float4 v0[4], v1[4], v2[4], v3[4];
#pragma unroll
        for (int i = 0; i < 4; ++i) v0[i] = p0[lane + 64 * i];
#pragma unroll
        for (int i = 0; i < 4; ++i) v1[i] = p1[lane + 64 * i];
#pragma unroll
        for (int i = 0; i < 4; ++i) v2[i] = p2[lane + 64 * i];
#pragma unroll
        for (int i = 0; i < 4; ++i) v3[i] = p3[lane + 64 * i];

        float s0 = 0.f, s1 = 0.f, s2 = 0.f, s3 = 0.f;
#pragma unroll
        for (int i = 0; i < 4; ++i) {
            s0 += (v0[i].x + v0[i].y) + (v0[i].z + v0[i].w);
            s1 += (v1[i].x + v1[i].y) + (v1[i].z + v1[i].w);
            s2 += (v2[i].x + v2[i].y) + (v2[i].z + v2[i].w);
            s3 += (v3[i].x + v3[i].y) + (v3[i].z + v3[i].w);
        }

        // 4 interleaved butterfly chains (ILP across the dependent shfls).
#pragma unroll
        for (int off = 32; off > 0; off >>= 1) {
            s0 += __shfl_down(s0, off, 64);
            s1 += __shfl_down(s1, off, 64);
            s2 += __shfl_down(s2, off, 64);
            s3 += __shfl_down(s3, off, 64);
        }
        if (lane == 0) {
            const float k = 1.0f / (float)SPATIAL;
            float4 r = make_float4(s0 * k, s1 * k, s2 * k, s3 * k);
            *(float4*)(out + OFF_EMB + c0) = r;   // c0 % 4 == 0 -> 16B aligned
        }
    } else {
        // ---- majority vote: one block per (b,t), 1024 threads ----
        const int bt = blockIdx.x - MEAN_BLOCKS;  // 0..383
        const int4* p4 = (const int4*)(gt + (size_t)bt * PIX_PER_BT);

        // 4096 int4 per block / 1024 threads = 4 int4/thread, fully unrolled.
        int4 w0 = p4[tid + 1024 * 0];
        int4 w1 = p4[tid + 1024 * 1];
        int4 w2 = p4[tid + 1024 * 2];
        int4 w3 = p4[tid + 1024 * 3];

        int cnt[NUM_CLASSES];
#pragma unroll
        for (int c = 0; c < NUM_CLASSES; ++c) {
            cnt[c] = (w0.x == c) + (w0.y == c) + (w0.z == c) + (w0.w == c)
                   + (w1.x == c) + (w1.y == c) + (w1.z == c) + (w1.w == c)
                   + (w2.x == c) + (w2.y == c) + (w2.z == c) + (w2.w == c)
                   + (w3.x == c) + (w3.y == c) + (w3.z == c) + (w3.w == c);
        }

        __shared__ int scnt[NUM_CLASSES];
        if (tid < NUM_CLASSES) scnt[tid] = 0;
        __syncthreads();

#pragma unroll
        for (int c = 0; c < NUM_CLASSES; ++c) {
            int s = cnt[c];
#pragma unroll
            for (int off = 32; off > 0; off >>= 1)
                s += __shfl_down(s, off, 64);
            if (lane == 0) atomicAdd(&scnt[c], s);
        }
        __syncthreads();

        if (tid == 0) {
            int best = 0, bc = scnt[0];
#pragma unroll
            for (int c = 1; c < NUM_CLASSES; ++c) {
                if (scnt[c] > bc) { bc = scnt[c]; best = c; }  // strict >: first-max tie-break
            }
            out[OFF_LAB + bt] = (float)best;
            out[OFF_POS + bt] = (float)positions[bt];
            if (bt < 16) out[OFF_SITS + bt] = (float)sits_id[bt];
        }
    }
}

extern "C" void kernel_launch(void* const* d_in, const int* in_sizes, int n_in,
                              void* d_out, int out_size, void* d_ws, size_t ws_size,
                              hipStream_t stream) {
    const float* out_temporal = (const float*)d_in[0];
    const int*   gt           = (const int*)d_in[1];
    const int*   positions    = (const int*)d_in[2];
    const int*   sits_id      = (const int*)d_in[3];
    float*       out          = (float*)d_out;

    fused_kernel<<<TOTAL_BLOCKS, 1024, 0, stream>>>(out_temporal, gt, positions, sits_id, out);
}

// Round 8
// 268.272 us; speedup vs baseline: 1.1046x; 1.0888x over previous
//
#include <hip/hip_runtime.h>
#include <hip/hip_bf16.h>

// Shapes (fixed by setup_inputs):
// out_temporal: (16,24,128,32,32) f32  -> 50331648 elems
// gt:           (16,24,128,128)   int  -> 6291456 elems
// positions:    (16,24)           int  -> 384
// sits_id:      (16,)             int  -> 16
//
// Outputs (flat f32 in d_out, return order):
//   emb    (16,24,1,128) = 49152 @ 0
//   labels (16,24,1)     = 384   @ 49152
//   sits_id (16,)        = 16    @ 49536
//   positions (16,24)    = 384   @ 49552

#define NCHAN       49152      // B*T*C
#define SPATIAL     1024       // 32*32
#define NBT         384        // B*T
#define PIX_PER_BT  16384      // 128*128
#define NUM_CLASSES 6

#define OFF_EMB   0
#define OFF_LAB   49152
#define OFF_SITS  49536
#define OFF_POS   49552

// clang native vectors — __builtin_nontemporal_load accepts these
// (HIP_vector_type float4/int4 are structs and are rejected).
typedef float f32x4 __attribute__((ext_vector_type(4)));
typedef int   i32x4 __attribute__((ext_vector_type(4)));

// Majority blocks FIRST so the 25 MB gt stream overlaps the 201 MB mean
// stream from dispatch t=0 instead of trailing serially.
#define MAJ_BLOCKS  NBT                     // 384
#define MEAN_BLOCKS 768                     // 768 * 16 waves * 4 ch = 49152
#define TOTAL_BLOCKS (MAJ_BLOCKS + MEAN_BLOCKS)

__global__ __launch_bounds__(1024) void fused_kernel(
        const float* __restrict__ in,
        const int*  __restrict__ gt,
        const int*  __restrict__ positions,
        const int*  __restrict__ sits_id,
        float* __restrict__ out) {
    const int tid  = threadIdx.x;
    const int lane = tid & 63;
    const int wave = tid >> 6;          // 0..15

    if (blockIdx.x >= MAJ_BLOCKS) {
        // ---- mean pooling: each wave reduces 4 channels (16 KB) ----
        const int c0 = (blockIdx.x - MAJ_BLOCKS) * 64 + wave * 4;
        const f32x4* p0 = (const f32x4*)(in + (size_t)(c0 + 0) * SPATIAL);
        const f32x4* p1 = (const f32x4*)(in + (size_t)(c0 + 1) * SPATIAL);
        const f32x4* p2 = (const f32x4*)(in + (size_t)(c0 + 2) * SPATIAL);
        const f32x4* p3 = (const f32x4*)(in + (size_t)(c0 + 3) * SPATIAL);

        // 16 independent nontemporal 16B loads in flight (read-once data;
        // skip L2/L3 allocation).
        f32x4 v0[4], v1[4], v2[4], v3[4];
#pragma unroll
        for (int i = 0; i < 4; ++i) v0[i] = __builtin_nontemporal_load(&p0[lane + 64 * i]);
#pragma unroll
        for (int i = 0; i < 4; ++i) v1[i] = __builtin_nontemporal_load(&p1[lane + 64 * i]);
#pragma unroll
        for (int i = 0; i < 4; ++i) v2[i] = __builtin_nontemporal_load(&p2[lane + 64 * i]);
#pragma unroll
        for (int i = 0; i < 4; ++i) v3[i] = __builtin_nontemporal_load(&p3[lane + 64 * i]);

        float s0 = 0.f, s1 = 0.f, s2 = 0.f, s3 = 0.f;
#pragma unroll
        for (int i = 0; i < 4; ++i) {
            s0 += (v0[i].x + v0[i].y) + (v0[i].z + v0[i].w);
            s1 += (v1[i].x + v1[i].y) + (v1[i].z + v1[i].w);
            s2 += (v2[i].x + v2[i].y) + (v2[i].z + v2[i].w);
            s3 += (v3[i].x + v3[i].y) + (v3[i].z + v3[i].w);
        }

        // 4 interleaved butterfly chains (ILP across the dependent shfls).
#pragma unroll
        for (int off = 32; off > 0; off >>= 1) {
            s0 += __shfl_down(s0, off, 64);
            s1 += __shfl_down(s1, off, 64);
            s2 += __shfl_down(s2, off, 64);
            s3 += __shfl_down(s3, off, 64);
        }
        if (lane == 0) {
            const float k = 1.0f / (float)SPATIAL;
            f32x4 r = { s0 * k, s1 * k, s2 * k, s3 * k };
            *(f32x4*)(out + OFF_EMB + c0) = r;   // c0 % 4 == 0 -> 16B aligned
        }
    } else {
        // ---- majority vote: one block per (b,t), 1024 threads ----
        const int bt = blockIdx.x;          // 0..383
        const i32x4* p4 = (const i32x4*)(gt + (size_t)bt * PIX_PER_BT);

        // 4096 int4 per block / 1024 threads = 4 int4/thread, fully unrolled.
        i32x4 w0 = __builtin_nontemporal_load(&p4[tid + 1024 * 0]);
        i32x4 w1 = __builtin_nontemporal_load(&p4[tid + 1024 * 1]);
        i32x4 w2 = __builtin_nontemporal_load(&p4[tid + 1024 * 2]);
        i32x4 w3 = __builtin_nontemporal_load(&p4[tid + 1024 * 3]);

        int cnt[NUM_CLASSES];
#pragma unroll
        for (int c = 0; c < NUM_CLASSES; ++c) {
            cnt[c] = (w0.x == c) + (w0.y == c) + (w0.z == c) + (w0.w == c)
                   + (w1.x == c) + (w1.y == c) + (w1.z == c) + (w1.w == c)
                   + (w2.x == c) + (w2.y == c) + (w2.z == c) + (w2.w == c)
                   + (w3.x == c) + (w3.y == c) + (w3.z == c) + (w3.w == c);
        }

        __shared__ int scnt[NUM_CLASSES];
        if (tid < NUM_CLASSES) scnt[tid] = 0;
        __syncthreads();

#pragma unroll
        for (int c = 0; c < NUM_CLASSES; ++c) {
            int s = cnt[c];
#pragma unroll
            for (int off = 32; off > 0; off >>= 1)
                s += __shfl_down(s, off, 64);
            if (lane == 0) atomicAdd(&scnt[c], s);
        }
        __syncthreads();

        if (tid == 0) {
            int best = 0, bc = scnt[0];
#pragma unroll
            for (int c = 1; c < NUM_CLASSES; ++c) {
                if (scnt[c] > bc) { bc = scnt[c]; best = c; }  // strict >: first-max tie-break
            }
            out[OFF_LAB + bt] = (float)best;
            out[OFF_POS + bt] = (float)positions[bt];
            if (bt < 16) out[OFF_SITS + bt] = (float)sits_id[bt];
        }
    }
}

extern "C" void kernel_launch(void* const* d_in, const int* in_sizes, int n_in,
                              void* d_out, int out_size, void* d_ws, size_t ws_size,
                              hipStream_t stream) {
    const float* out_temporal = (const float*)d_in[0];
    const int*   gt           = (const int*)d_in[1];
    const int*   positions    = (const int*)d_in[2];
    const int*   sits_id      = (const int*)d_in[3];
    float*       out          = (float*)d_out;

    fused_kernel<<<TOTAL_BLOCKS, 1024, 0, stream>>>(out_temporal, gt, positions, sits_id, out);
}